// Round 8
// baseline (345.673 us; speedup 1.0000x reference)
//
#include <hip/hip_runtime.h>
#include <cstddef>

// ---------------------------------------------------------------------------
// GCN forward: 3 x ( h@W bf16 MFMA -> L2-sliced CSR segsum -> LN(+ReLU) )
// N=50000, E=800000, D: 128 -> 128 -> 128 -> 64.
// R8 change vs R7 (passing): aggregation split into feature slices of 32
// (3.2 MB per slice < 4 MB per-XCD L2) writing fp32 pre-LN partials, plus a
// separate LN/pack kernel. 8-way edge-group parallelism. GEMM + cvt kernels
// bit-identical to R7.
// ---------------------------------------------------------------------------

typedef __attribute__((ext_vector_type(8))) short bf16x8;
typedef __attribute__((ext_vector_type(4))) float floatx4;
typedef __attribute__((ext_vector_type(4))) unsigned int uintx4;
typedef __attribute__((ext_vector_type(2))) unsigned int uintx2;

static __device__ __forceinline__ unsigned int f2bf(float f) {
    // round-to-nearest-even f32 -> bf16, returned in low 16 bits
    union { float f; unsigned int u; } v; v.f = f;
    unsigned int u = v.u;
    u += 0x7fffu + ((u >> 16) & 1u);
    return u >> 16;
}
static __device__ __forceinline__ float bf_lo(unsigned int p) {
    union { unsigned int u; float f; } v; v.u = p << 16; return v.f;
}
static __device__ __forceinline__ float bf_hi(unsigned int p) {
    union { unsigned int u; float f; } v; v.u = p & 0xffff0000u; return v.f;
}

// ---- feat fp32 -> packed-bf16 (uint) --------------------------------------
__global__ __launch_bounds__(256) void cvt_feat(const float* __restrict__ in,
                                                unsigned int* __restrict__ out,
                                                int n8) {
    int i = blockIdx.x * 256 + threadIdx.x;
    if (i < n8) {
        float4 a = ((const float4*)in)[i * 2];
        float4 b = ((const float4*)in)[i * 2 + 1];
        uintx4 p;
        p.x = (f2bf(a.y) << 16) | f2bf(a.x);
        p.y = (f2bf(a.w) << 16) | f2bf(a.z);
        p.z = (f2bf(b.y) << 16) | f2bf(b.x);
        p.w = (f2bf(b.w) << 16) | f2bf(b.z);
        ((uintx4*)out)[i] = p;
    }
}

// ---- W[k][n] fp32 -> Wt[n][kk] packed bf16 pairs (uint), 3 matrices --------
__global__ __launch_bounds__(256) void cvt_w(const float* __restrict__ W0,
                                             const float* __restrict__ W1,
                                             const float* __restrict__ W2,
                                             unsigned int* __restrict__ Wt) {
    const int m = blockIdx.x >> 4;
    const int slice = blockIdx.x & 15;
    const float* W = (m == 0) ? W0 : (m == 1) ? W1 : W2;
    const int ncols = (m == 2) ? 64 : 128;
    unsigned int* dst = Wt + m * 128 * 64;
    const int total = ncols * 64;
    for (int idx = slice * 256 + threadIdx.x; idx < total; idx += 16 * 256) {
        int kk = idx / ncols;
        int n  = idx - kk * ncols;
        unsigned int lo = f2bf(W[(size_t)(2 * kk) * ncols + n]);
        unsigned int hi = f2bf(W[(size_t)(2 * kk + 1) * ncols + n]);
        dst[(size_t)n * 64 + kk] = (hi << 16) | lo;
    }
}

// ---- bf16 MFMA GEMM (bit-identical to R7's passing kernel) ----------------
template <int NCOLS>
__global__ __launch_bounds__(256) void gemm_mfma(const unsigned int* __restrict__ A,
                                                 const unsigned int* __restrict__ Wt,
                                                 unsigned int* __restrict__ C,
                                                 int M) {
    const int lane = threadIdx.x & 63;
    const int wave = threadIdx.x >> 6;
    const int row0 = blockIdx.x * 64 + wave * 16;
    const int quad = lane >> 4;
    const int mcol = lane & 15;
    const int arow_idx = row0 + mcol;
    const int aload = (arow_idx < M) ? arow_idx : (M - 1);

    constexpr int NT = NCOLS / 16;
    floatx4 acc[NT];
    #pragma unroll
    for (int t = 0; t < NT; ++t) acc[t] = (floatx4){0.f, 0.f, 0.f, 0.f};

    const unsigned int* arow = A + (size_t)aload * 64 + quad * 4;

    #pragma unroll
    for (int k0 = 0; k0 < 128; k0 += 32) {
        uintx4 ap = *(const uintx4*)(arow + k0 / 2);
        bf16x8 a = __builtin_bit_cast(bf16x8, ap);

        const int koff = (k0 + quad * 8) >> 1;
        #pragma unroll
        for (int t = 0; t < NT; ++t) {
            const unsigned int* brow = Wt + (size_t)(t * 16 + mcol) * 64 + koff;
            uintx4 bp = *(const uintx4*)brow;
            bf16x8 b = __builtin_bit_cast(bf16x8, bp);
            acc[t] = __builtin_amdgcn_mfma_f32_16x16x32_bf16(a, b, acc[t], 0, 0, 0);
        }
    }

    const int rowStride = NCOLS >> 1;
    #pragma unroll
    for (int t = 0; t < NT; ++t) {
        #pragma unroll
        for (int r = 0; r < 4; ++r) {
            unsigned int mybf = f2bf(acc[t][r]);
            unsigned int pair = __shfl_xor(mybf, 1, 64);
            int orow = row0 + quad * 4 + r;
            if (orow < M && (mcol & 1) == 0) {
                unsigned int packed = (pair << 16) | mybf;
                C[(size_t)orow * rowStride + t * 8 + (mcol >> 1)] = packed;
            }
        }
    }
}

// ---- L2-sliced CSR segment-sum: 32 features per slice ----------------------
// grid = (ceil(N/4), D/32). Block = 4 waves, wave = one node's slice.
// Lane = (g, sl): g = edge group (8), sl = feature sub-lane (8, uintx2 each).
// Writes fp32 pre-LN partial rows to hpart[N][D].
template <int D>
__global__ __launch_bounds__(256) void agg_slice(const unsigned int* __restrict__ xw,
                                                 const int* __restrict__ ptr,
                                                 const int* __restrict__ col,
                                                 float* __restrict__ hpart, int N) {
    const int node = blockIdx.x * 4 + (threadIdx.x >> 6);
    if (node >= N) return;
    const int slice = blockIdx.y;
    const int lane = threadIdx.x & 63;
    const int g  = lane >> 3;     // 0..7
    const int sl = lane & 7;      // 0..7
    const int s = ptr[node];
    const int e = ptr[node + 1];

    float a0 = 0.f, a1 = 0.f, a2 = 0.f, a3 = 0.f;
    const unsigned int* base = xw + slice * 16 + sl * 2;
    for (int i = s + g; i < e; i += 8) {
        const int src = col[i];
        uintx2 v = *(const uintx2*)(base + (size_t)src * (D / 2));
        a0 += bf_lo(v.x); a1 += bf_hi(v.x);
        a2 += bf_lo(v.y); a3 += bf_hi(v.y);
    }
    // combine the 8 edge groups (lane bits 3,4,5)
    #pragma unroll
    for (int m = 8; m <= 32; m <<= 1) {
        a0 += __shfl_xor(a0, m, 64);
        a1 += __shfl_xor(a1, m, 64);
        a2 += __shfl_xor(a2, m, 64);
        a3 += __shfl_xor(a3, m, 64);
    }
    if (g == 0) {
        float4 o; o.x = a0; o.y = a1; o.z = a2; o.w = a3;
        *(float4*)(hpart + (size_t)node * D + slice * 32 + sl * 4) = o;
    }
}

// ---- LN + ReLU + bf16-pack, D=128 (layers 0,1) -----------------------------
__global__ __launch_bounds__(256) void ln_pack128(const float* __restrict__ hpart,
                                                  unsigned int* __restrict__ out,
                                                  int N) {
    const int node = blockIdx.x * 4 + (threadIdx.x >> 6);
    if (node >= N) return;
    const int lane = threadIdx.x & 63;
    float2 v = *(const float2*)(hpart + (size_t)node * 128 + lane * 2);
    float s1 = v.x + v.y;
    float s2 = v.x * v.x + v.y * v.y;
    #pragma unroll
    for (int m = 32; m >= 1; m >>= 1) {
        s1 += __shfl_xor(s1, m, 64);
        s2 += __shfl_xor(s2, m, 64);
    }
    const float mean = s1 * (1.0f / 128.0f);
    const float var  = s2 * (1.0f / 128.0f) - mean * mean;
    const float inv  = rsqrtf(var + 1e-5f);
    float o0 = fmaxf((v.x - mean) * inv, 0.f);
    float o1 = fmaxf((v.y - mean) * inv, 0.f);
    out[(size_t)node * 64 + lane] = (f2bf(o1) << 16) | f2bf(o0);
}

// ---- LN, D=64, fp32 out, no ReLU (final layer) -----------------------------
__global__ __launch_bounds__(256) void ln_out64(const float* __restrict__ hpart,
                                                float* __restrict__ out, int N) {
    const int node = blockIdx.x * 4 + (threadIdx.x >> 6);
    if (node >= N) return;
    const int lane = threadIdx.x & 63;
    float v = hpart[(size_t)node * 64 + lane];
    float s1 = v;
    float s2 = v * v;
    #pragma unroll
    for (int m = 32; m >= 1; m >>= 1) {
        s1 += __shfl_xor(s1, m, 64);
        s2 += __shfl_xor(s2, m, 64);
    }
    const float mean = s1 * (1.0f / 64.0f);
    const float var  = s2 * (1.0f / 64.0f) - mean * mean;
    const float inv  = rsqrtf(var + 1e-5f);
    out[(size_t)node * 64 + lane] = (v - mean) * inv;
}

extern "C" void kernel_launch(void* const* d_in, const int* in_sizes, int n_in,
                              void* d_out, int out_size, void* d_ws, size_t ws_size,
                              hipStream_t stream) {
    const float* feat = (const float*)d_in[0];   // [N,128]
    const float* W0   = (const float*)d_in[1];   // [128,128]
    const float* W1   = (const float*)d_in[2];   // [128,128]
    const float* W2   = (const float*)d_in[3];   // [128,64]
    const int*   ptr  = (const int*)d_in[4];     // [N+1]
    const int*   col  = (const int*)d_in[5];     // [E]
    // d_in[6] = edge_rows, unused (CSR ptr encodes the same segments)

    const int N = in_sizes[4] - 1;               // 50000

    unsigned int* xwp   = (unsigned int*)d_ws;                 // [N,64] uint (bf16x2)
    unsigned int* hb    = xwp + (size_t)N * 64;                // [N,64] uint (bf16x2)
    unsigned int* fb    = hb + (size_t)N * 64;                 // [N,64] uint (bf16 feat)
    unsigned int* WtP   = fb + (size_t)N * 64;                 // 3 x [128,64] uint
    float*        hpart = (float*)(WtP + 3 * 128 * 64);        // [N,128] fp32 pre-LN
    float*        out   = (float*)d_out;                       // [N,64]

    const int gemmBlocks = (N + 63) / 64;        // 782
    const int nodeBlocks = (N + 3) / 4;          // 12500

    cvt_feat<<<(N * 16 + 255) / 256, 256, 0, stream>>>(feat, fb, N * 16);
    cvt_w<<<48, 256, 0, stream>>>(W0, W1, W2, WtP);

    // Layer 0
    gemm_mfma<128><<<gemmBlocks, 256, 0, stream>>>(fb, WtP, xwp, N);
    agg_slice<128><<<dim3(nodeBlocks, 4), 256, 0, stream>>>(xwp, ptr, col, hpart, N);
    ln_pack128<<<nodeBlocks, 256, 0, stream>>>(hpart, hb, N);
    // Layer 1
    gemm_mfma<128><<<gemmBlocks, 256, 0, stream>>>(hb, WtP + 128 * 64, xwp, N);
    agg_slice<128><<<dim3(nodeBlocks, 4), 256, 0, stream>>>(xwp, ptr, col, hpart, N);
    ln_pack128<<<nodeBlocks, 256, 0, stream>>>(hpart, hb, N);
    // Layer 2 (D_out=64, no ReLU, fp32 out)
    gemm_mfma<64><<<gemmBlocks, 256, 0, stream>>>(hb, WtP + 2 * 128 * 64, xwp, N);
    agg_slice<64><<<dim3(nodeBlocks, 2), 256, 0, stream>>>(xwp, ptr, col, hpart, N);
    ln_out64<<<nodeBlocks, 256, 0, stream>>>(hpart, out, N);
}

// Round 9
// 262.928 us; speedup vs baseline: 1.3147x; 1.3147x over previous
//
#include <hip/hip_runtime.h>
#include <cstddef>

// ---------------------------------------------------------------------------
// GCN forward: 3 x ( h@W bf16 MFMA -> packed-bf16 xw -> CSR segsum+LN(+ReLU) )
// N=50000, E=800000, D: 128 -> 128 -> 128 -> 64.
// R9 = R7 (passing, 249us) with agg rewritten for 8-edges-in-flight MLP:
// lane=(g 0..7 edge group, sl 0..7 feature sublane), 2x uintx4 per lane per
// edge (full 256B row across 8 sublanes). R8's slicing reverted (FETCH went
// UP 83->111MB: co-resident slices defeat L2 residency + col re-reads).
// GEMM + cvt kernels bit-identical to R7.
// ---------------------------------------------------------------------------

typedef __attribute__((ext_vector_type(8))) short bf16x8;
typedef __attribute__((ext_vector_type(4))) float floatx4;
typedef __attribute__((ext_vector_type(4))) unsigned int uintx4;

static __device__ __forceinline__ unsigned int f2bf(float f) {
    // round-to-nearest-even f32 -> bf16, returned in low 16 bits
    union { float f; unsigned int u; } v; v.f = f;
    unsigned int u = v.u;
    u += 0x7fffu + ((u >> 16) & 1u);
    return u >> 16;
}
static __device__ __forceinline__ float bf_lo(unsigned int p) {
    union { unsigned int u; float f; } v; v.u = p << 16; return v.f;
}
static __device__ __forceinline__ float bf_hi(unsigned int p) {
    union { unsigned int u; float f; } v; v.u = p & 0xffff0000u; return v.f;
}

// ---- feat fp32 -> packed-bf16 (uint) --------------------------------------
__global__ __launch_bounds__(256) void cvt_feat(const float* __restrict__ in,
                                                unsigned int* __restrict__ out,
                                                int n8) {
    int i = blockIdx.x * 256 + threadIdx.x;
    if (i < n8) {
        float4 a = ((const float4*)in)[i * 2];
        float4 b = ((const float4*)in)[i * 2 + 1];
        uintx4 p;
        p.x = (f2bf(a.y) << 16) | f2bf(a.x);
        p.y = (f2bf(a.w) << 16) | f2bf(a.z);
        p.z = (f2bf(b.y) << 16) | f2bf(b.x);
        p.w = (f2bf(b.w) << 16) | f2bf(b.z);
        ((uintx4*)out)[i] = p;
    }
}

// ---- W[k][n] fp32 -> Wt[n][kk] packed bf16 pairs (uint), 3 matrices --------
__global__ __launch_bounds__(256) void cvt_w(const float* __restrict__ W0,
                                             const float* __restrict__ W1,
                                             const float* __restrict__ W2,
                                             unsigned int* __restrict__ Wt) {
    const int m = blockIdx.x >> 4;
    const int slice = blockIdx.x & 15;
    const float* W = (m == 0) ? W0 : (m == 1) ? W1 : W2;
    const int ncols = (m == 2) ? 64 : 128;
    unsigned int* dst = Wt + m * 128 * 64;
    const int total = ncols * 64;
    for (int idx = slice * 256 + threadIdx.x; idx < total; idx += 16 * 256) {
        int kk = idx / ncols;
        int n  = idx - kk * ncols;
        unsigned int lo = f2bf(W[(size_t)(2 * kk) * ncols + n]);
        unsigned int hi = f2bf(W[(size_t)(2 * kk + 1) * ncols + n]);
        dst[(size_t)n * 64 + kk] = (hi << 16) | lo;
    }
}

// ---- bf16 MFMA GEMM (bit-identical to R7's passing kernel) ----------------
template <int NCOLS>
__global__ __launch_bounds__(256) void gemm_mfma(const unsigned int* __restrict__ A,
                                                 const unsigned int* __restrict__ Wt,
                                                 unsigned int* __restrict__ C,
                                                 int M) {
    const int lane = threadIdx.x & 63;
    const int wave = threadIdx.x >> 6;
    const int row0 = blockIdx.x * 64 + wave * 16;
    const int quad = lane >> 4;
    const int mcol = lane & 15;
    const int arow_idx = row0 + mcol;
    const int aload = (arow_idx < M) ? arow_idx : (M - 1);

    constexpr int NT = NCOLS / 16;
    floatx4 acc[NT];
    #pragma unroll
    for (int t = 0; t < NT; ++t) acc[t] = (floatx4){0.f, 0.f, 0.f, 0.f};

    const unsigned int* arow = A + (size_t)aload * 64 + quad * 4;

    #pragma unroll
    for (int k0 = 0; k0 < 128; k0 += 32) {
        uintx4 ap = *(const uintx4*)(arow + k0 / 2);
        bf16x8 a = __builtin_bit_cast(bf16x8, ap);

        const int koff = (k0 + quad * 8) >> 1;
        #pragma unroll
        for (int t = 0; t < NT; ++t) {
            const unsigned int* brow = Wt + (size_t)(t * 16 + mcol) * 64 + koff;
            uintx4 bp = *(const uintx4*)brow;
            bf16x8 b = __builtin_bit_cast(bf16x8, bp);
            acc[t] = __builtin_amdgcn_mfma_f32_16x16x32_bf16(a, b, acc[t], 0, 0, 0);
        }
    }

    const int rowStride = NCOLS >> 1;
    #pragma unroll
    for (int t = 0; t < NT; ++t) {
        #pragma unroll
        for (int r = 0; r < 4; ++r) {
            unsigned int mybf = f2bf(acc[t][r]);
            unsigned int pair = __shfl_xor(mybf, 1, 64);
            int orow = row0 + quad * 4 + r;
            if (orow < M && (mcol & 1) == 0) {
                unsigned int packed = (pair << 16) | mybf;
                C[(size_t)orow * rowStride + t * 8 + (mcol >> 1)] = packed;
            }
        }
    }
}

// ---- fused CSR segsum + LN + ReLU, D=128, packed-bf16 out ------------------
// Wave per node; lane=(g 0..7 edge group, sl 0..7 sublane). Per edge each
// lane issues two independent uintx4 loads (8 sublanes x 32B = 256B row).
// 16 gathers in flight per wave; avg trip count = deg/8 = 2.
__global__ __launch_bounds__(256) void agg_ln128(const unsigned int* __restrict__ xw,
                                                 const int* __restrict__ ptr,
                                                 const int* __restrict__ col,
                                                 unsigned int* __restrict__ out,
                                                 int N) {
    const int node = blockIdx.x * 4 + (threadIdx.x >> 6);
    if (node >= N) return;
    const int lane = threadIdx.x & 63;
    const int g  = lane >> 3;     // 0..7 edge group
    const int sl = lane & 7;      // 0..7 feature sublane (owns 16 features)
    const int s = ptr[node];
    const int e = ptr[node + 1];

    float acc[16] = {};
    const unsigned int* base = xw + sl * 8;
    for (int i = s + g; i < e; i += 8) {
        const unsigned int* row = base + (size_t)col[i] * 64;
        uintx4 v0 = *(const uintx4*)row;
        uintx4 v1 = *(const uintx4*)(row + 4);
        acc[0]  += bf_lo(v0.x); acc[1]  += bf_hi(v0.x);
        acc[2]  += bf_lo(v0.y); acc[3]  += bf_hi(v0.y);
        acc[4]  += bf_lo(v0.z); acc[5]  += bf_hi(v0.z);
        acc[6]  += bf_lo(v0.w); acc[7]  += bf_hi(v0.w);
        acc[8]  += bf_lo(v1.x); acc[9]  += bf_hi(v1.x);
        acc[10] += bf_lo(v1.y); acc[11] += bf_hi(v1.y);
        acc[12] += bf_lo(v1.z); acc[13] += bf_hi(v1.z);
        acc[14] += bf_lo(v1.w); acc[15] += bf_hi(v1.w);
    }
    // combine the 8 edge groups (lane bits 3,4,5)
    #pragma unroll
    for (int j = 0; j < 16; ++j) {
        acc[j] += __shfl_xor(acc[j], 8, 64);
        acc[j] += __shfl_xor(acc[j], 16, 64);
        acc[j] += __shfl_xor(acc[j], 32, 64);
    }
    // LN stats over the 8 sublanes (lane bits 0,1,2)
    float s1 = 0.f, s2 = 0.f;
    #pragma unroll
    for (int j = 0; j < 16; ++j) { s1 += acc[j]; s2 += acc[j] * acc[j]; }
    #pragma unroll
    for (int m = 4; m >= 1; m >>= 1) {
        s1 += __shfl_xor(s1, m, 64);
        s2 += __shfl_xor(s2, m, 64);
    }
    const float mean = s1 * (1.0f / 128.0f);
    const float var  = s2 * (1.0f / 128.0f) - mean * mean;
    const float inv  = rsqrtf(var + 1e-5f);

    // ReLU + pack; store split across g=0 (first 8 feats) / g=1 (last 8)
    if (g < 2) {
        const int o = g * 8;
        float r[8];
        #pragma unroll
        for (int j = 0; j < 8; ++j)
            r[j] = fmaxf((acc[o + j] - mean) * inv, 0.f);
        uintx4 p;
        p.x = (f2bf(r[1]) << 16) | f2bf(r[0]);
        p.y = (f2bf(r[3]) << 16) | f2bf(r[2]);
        p.z = (f2bf(r[5]) << 16) | f2bf(r[4]);
        p.w = (f2bf(r[7]) << 16) | f2bf(r[6]);
        *(uintx4*)(out + (size_t)node * 64 + sl * 8 + g * 4) = p;
    }
}

// ---- fused CSR segsum + LN, D=64, fp32 out, no ReLU (final layer) ----------
// Same structure; one uintx4 per lane per edge (8 sublanes x 16B = 128B row).
__global__ __launch_bounds__(256) void agg_ln64(const unsigned int* __restrict__ xw,
                                                const int* __restrict__ ptr,
                                                const int* __restrict__ col,
                                                float* __restrict__ out, int N) {
    const int node = blockIdx.x * 4 + (threadIdx.x >> 6);
    if (node >= N) return;
    const int lane = threadIdx.x & 63;
    const int g  = lane >> 3;     // 0..7 edge group
    const int sl = lane & 7;      // 0..7 sublane (owns 8 features)
    const int s = ptr[node];
    const int e = ptr[node + 1];

    float acc[8] = {};
    const unsigned int* base = xw + sl * 4;
    for (int i = s + g; i < e; i += 8) {
        uintx4 v = *(const uintx4*)(base + (size_t)col[i] * 32);
        acc[0] += bf_lo(v.x); acc[1] += bf_hi(v.x);
        acc[2] += bf_lo(v.y); acc[3] += bf_hi(v.y);
        acc[4] += bf_lo(v.z); acc[5] += bf_hi(v.z);
        acc[6] += bf_lo(v.w); acc[7] += bf_hi(v.w);
    }
    #pragma unroll
    for (int j = 0; j < 8; ++j) {
        acc[j] += __shfl_xor(acc[j], 8, 64);
        acc[j] += __shfl_xor(acc[j], 16, 64);
        acc[j] += __shfl_xor(acc[j], 32, 64);
    }
    float s1 = 0.f, s2 = 0.f;
    #pragma unroll
    for (int j = 0; j < 8; ++j) { s1 += acc[j]; s2 += acc[j] * acc[j]; }
    #pragma unroll
    for (int m = 4; m >= 1; m >>= 1) {
        s1 += __shfl_xor(s1, m, 64);
        s2 += __shfl_xor(s2, m, 64);
    }
    const float mean = s1 * (1.0f / 64.0f);
    const float var  = s2 * (1.0f / 64.0f) - mean * mean;
    const float inv  = rsqrtf(var + 1e-5f);

    if (g < 2) {
        const int o = g * 4;
        float4 r;
        r.x = (acc[o + 0] - mean) * inv;
        r.y = (acc[o + 1] - mean) * inv;
        r.z = (acc[o + 2] - mean) * inv;
        r.w = (acc[o + 3] - mean) * inv;
        *(float4*)(out + (size_t)node * 64 + sl * 8 + g * 4) = r;
    }
}

extern "C" void kernel_launch(void* const* d_in, const int* in_sizes, int n_in,
                              void* d_out, int out_size, void* d_ws, size_t ws_size,
                              hipStream_t stream) {
    const float* feat = (const float*)d_in[0];   // [N,128]
    const float* W0   = (const float*)d_in[1];   // [128,128]
    const float* W1   = (const float*)d_in[2];   // [128,128]
    const float* W2   = (const float*)d_in[3];   // [128,64]
    const int*   ptr  = (const int*)d_in[4];     // [N+1]
    const int*   col  = (const int*)d_in[5];     // [E]
    // d_in[6] = edge_rows, unused (CSR ptr encodes the same segments)

    const int N = in_sizes[4] - 1;               // 50000

    unsigned int* xwp = (unsigned int*)d_ws;                 // [N,64] uint (bf16x2)
    unsigned int* hb  = xwp + (size_t)N * 64;                // [N,64] uint (bf16x2)
    unsigned int* fb  = hb + (size_t)N * 64;                 // [N,64] uint (bf16 feat)
    unsigned int* WtP = fb + (size_t)N * 64;                 // 3 x [128,64] uint
    float*        out = (float*)d_out;                       // [N,64]

    const int gemmBlocks = (N + 63) / 64;        // 782
    const int nodeBlocks = (N + 3) / 4;          // 12500

    cvt_feat<<<(N * 16 + 255) / 256, 256, 0, stream>>>(feat, fb, N * 16);
    cvt_w<<<48, 256, 0, stream>>>(W0, W1, W2, WtP);

    // Layer 0
    gemm_mfma<128><<<gemmBlocks, 256, 0, stream>>>(fb, WtP, xwp, N);
    agg_ln128<<<nodeBlocks, 256, 0, stream>>>(xwp, ptr, col, hb, N);
    // Layer 1
    gemm_mfma<128><<<gemmBlocks, 256, 0, stream>>>(hb, WtP + 128 * 64, xwp, N);
    agg_ln128<<<nodeBlocks, 256, 0, stream>>>(xwp, ptr, col, hb, N);
    // Layer 2 (D_out=64, no ReLU, fp32 out)
    gemm_mfma<64><<<gemmBlocks, 256, 0, stream>>>(hb, WtP + 2 * 128 * 64, xwp, N);
    agg_ln64<<<nodeBlocks, 256, 0, stream>>>(xwp, ptr, col, out, N);
}

// Round 10
// 227.837 us; speedup vs baseline: 1.5172x; 1.1540x over previous
//
#include <hip/hip_runtime.h>
#include <cstddef>

// ---------------------------------------------------------------------------
// GCN forward: 3 x ( h@W bf16 MFMA -> packed-bf16 xw -> CSR segsum+LN(+ReLU) )
// N=50000, E=800000, D: 128 -> 128 -> 128 -> 64.
// R10: agg back to R6's 4x16 lane layout (optimal 4 sectors/edge) + unroll-2
// (8 edges in flight, two independent acc sets). GEMM moved to 1-wave blocks
// (3125 blocks vs 782: kills 3.05-blocks/CU tail quantization). R9's 8x8 agg
// reverted (VALUBusy 83%, 2x sector touches/edge).
// ---------------------------------------------------------------------------

typedef __attribute__((ext_vector_type(8))) short bf16x8;
typedef __attribute__((ext_vector_type(4))) float floatx4;
typedef __attribute__((ext_vector_type(4))) unsigned int uintx4;
typedef __attribute__((ext_vector_type(2))) unsigned int uintx2;

static __device__ __forceinline__ unsigned int f2bf(float f) {
    union { float f; unsigned int u; } v; v.f = f;
    unsigned int u = v.u;
    u += 0x7fffu + ((u >> 16) & 1u);
    return u >> 16;
}
static __device__ __forceinline__ float bf_lo(unsigned int p) {
    union { unsigned int u; float f; } v; v.u = p << 16; return v.f;
}
static __device__ __forceinline__ float bf_hi(unsigned int p) {
    union { unsigned int u; float f; } v; v.u = p & 0xffff0000u; return v.f;
}

// ---- feat fp32 -> packed-bf16 (uint) --------------------------------------
__global__ __launch_bounds__(256) void cvt_feat(const float* __restrict__ in,
                                                unsigned int* __restrict__ out,
                                                int n8) {
    int i = blockIdx.x * 256 + threadIdx.x;
    if (i < n8) {
        float4 a = ((const float4*)in)[i * 2];
        float4 b = ((const float4*)in)[i * 2 + 1];
        uintx4 p;
        p.x = (f2bf(a.y) << 16) | f2bf(a.x);
        p.y = (f2bf(a.w) << 16) | f2bf(a.z);
        p.z = (f2bf(b.y) << 16) | f2bf(b.x);
        p.w = (f2bf(b.w) << 16) | f2bf(b.z);
        ((uintx4*)out)[i] = p;
    }
}

// ---- W[k][n] fp32 -> Wt[n][kk] packed bf16 pairs (uint), 3 matrices --------
__global__ __launch_bounds__(256) void cvt_w(const float* __restrict__ W0,
                                             const float* __restrict__ W1,
                                             const float* __restrict__ W2,
                                             unsigned int* __restrict__ Wt) {
    const int m = blockIdx.x >> 4;
    const int slice = blockIdx.x & 15;
    const float* W = (m == 0) ? W0 : (m == 1) ? W1 : W2;
    const int ncols = (m == 2) ? 64 : 128;
    unsigned int* dst = Wt + m * 128 * 64;
    const int total = ncols * 64;
    for (int idx = slice * 256 + threadIdx.x; idx < total; idx += 16 * 256) {
        int kk = idx / ncols;
        int n  = idx - kk * ncols;
        unsigned int lo = f2bf(W[(size_t)(2 * kk) * ncols + n]);
        unsigned int hi = f2bf(W[(size_t)(2 * kk + 1) * ncols + n]);
        dst[(size_t)n * 64 + kk] = (hi << 16) | lo;
    }
}

// ---- bf16 MFMA GEMM, 1 wave per block (16 rows x NCOLS) --------------------
// Body identical to R7's proven kernel; only the grid mapping changed.
template <int NCOLS>
__global__ __launch_bounds__(64) void gemm_mfma(const unsigned int* __restrict__ A,
                                                const unsigned int* __restrict__ Wt,
                                                unsigned int* __restrict__ C,
                                                int M) {
    const int lane = threadIdx.x;
    const int row0 = blockIdx.x * 16;
    const int quad = lane >> 4;
    const int mcol = lane & 15;
    const int arow_idx = row0 + mcol;
    const int aload = (arow_idx < M) ? arow_idx : (M - 1);

    constexpr int NT = NCOLS / 16;
    floatx4 acc[NT];
    #pragma unroll
    for (int t = 0; t < NT; ++t) acc[t] = (floatx4){0.f, 0.f, 0.f, 0.f};

    const unsigned int* arow = A + (size_t)aload * 64 + quad * 4;

    #pragma unroll
    for (int k0 = 0; k0 < 128; k0 += 32) {
        uintx4 ap = *(const uintx4*)(arow + k0 / 2);
        bf16x8 a = __builtin_bit_cast(bf16x8, ap);

        const int koff = (k0 + quad * 8) >> 1;
        #pragma unroll
        for (int t = 0; t < NT; ++t) {
            const unsigned int* brow = Wt + (size_t)(t * 16 + mcol) * 64 + koff;
            uintx4 bp = *(const uintx4*)brow;
            bf16x8 b = __builtin_bit_cast(bf16x8, bp);
            acc[t] = __builtin_amdgcn_mfma_f32_16x16x32_bf16(a, b, acc[t], 0, 0, 0);
        }
    }

    const int rowStride = NCOLS >> 1;
    #pragma unroll
    for (int t = 0; t < NT; ++t) {
        #pragma unroll
        for (int r = 0; r < 4; ++r) {
            unsigned int mybf = f2bf(acc[t][r]);
            unsigned int pair = __shfl_xor(mybf, 1, 64);
            int orow = row0 + quad * 4 + r;
            if (orow < M && (mcol & 1) == 0) {
                unsigned int packed = (pair << 16) | mybf;
                C[(size_t)orow * rowStride + t * 8 + (mcol >> 1)] = packed;
            }
        }
    }
}

// ---- fused CSR segsum + LN + ReLU, D=128, packed-bf16 out ------------------
// R6 lane layout (g 0..3 edge group, sl 0..15 sublane, uintx4 = 16B/lane,
// 4 sectors/edge) + unroll-2: edges i and i+4 in flight with independent
// accumulator sets.
__global__ __launch_bounds__(256) void agg_ln128(const unsigned int* __restrict__ xw,
                                                 const int* __restrict__ ptr,
                                                 const int* __restrict__ col,
                                                 unsigned int* __restrict__ out,
                                                 int N) {
    const int node = blockIdx.x * 4 + (threadIdx.x >> 6);
    if (node >= N) return;
    const int lane = threadIdx.x & 63;
    const int g  = lane >> 4;     // 0..3 edge group
    const int sl = lane & 15;     // 0..15 sublane (owns 8 features)
    const int s = ptr[node];
    const int e = ptr[node + 1];

    float accA[8] = {}, accB[8] = {};
    const unsigned int* base = xw + sl * 4;
    int i = s + g;
    for (; i + 4 < e; i += 8) {
        uintx4 v0 = *(const uintx4*)(base + (size_t)col[i] * 64);
        uintx4 v1 = *(const uintx4*)(base + (size_t)col[i + 4] * 64);
        accA[0] += bf_lo(v0.x); accA[1] += bf_hi(v0.x);
        accA[2] += bf_lo(v0.y); accA[3] += bf_hi(v0.y);
        accA[4] += bf_lo(v0.z); accA[5] += bf_hi(v0.z);
        accA[6] += bf_lo(v0.w); accA[7] += bf_hi(v0.w);
        accB[0] += bf_lo(v1.x); accB[1] += bf_hi(v1.x);
        accB[2] += bf_lo(v1.y); accB[3] += bf_hi(v1.y);
        accB[4] += bf_lo(v1.z); accB[5] += bf_hi(v1.z);
        accB[6] += bf_lo(v1.w); accB[7] += bf_hi(v1.w);
    }
    if (i < e) {
        uintx4 v0 = *(const uintx4*)(base + (size_t)col[i] * 64);
        accA[0] += bf_lo(v0.x); accA[1] += bf_hi(v0.x);
        accA[2] += bf_lo(v0.y); accA[3] += bf_hi(v0.y);
        accA[4] += bf_lo(v0.z); accA[5] += bf_hi(v0.z);
        accA[6] += bf_lo(v0.w); accA[7] += bf_hi(v0.w);
    }

    float acc[8];
    #pragma unroll
    for (int j = 0; j < 8; ++j) acc[j] = accA[j] + accB[j];

    // combine the 4 edge groups (lane bits 4,5)
    #pragma unroll
    for (int j = 0; j < 8; ++j) {
        acc[j] += __shfl_xor(acc[j], 16, 64);
        acc[j] += __shfl_xor(acc[j], 32, 64);
    }
    // LN stats over the 16 sublanes (lane bits 0..3)
    float s1 = 0.f, s2 = 0.f;
    #pragma unroll
    for (int j = 0; j < 8; ++j) { s1 += acc[j]; s2 += acc[j] * acc[j]; }
    #pragma unroll
    for (int m = 8; m >= 1; m >>= 1) {
        s1 += __shfl_xor(s1, m, 64);
        s2 += __shfl_xor(s2, m, 64);
    }
    const float mean = s1 * (1.0f / 128.0f);
    const float var  = s2 * (1.0f / 128.0f) - mean * mean;
    const float inv  = rsqrtf(var + 1e-5f);

    if (g == 0) {
        float o[8];
        #pragma unroll
        for (int j = 0; j < 8; ++j)
            o[j] = fmaxf((acc[j] - mean) * inv, 0.f);
        uintx4 p;
        p.x = (f2bf(o[1]) << 16) | f2bf(o[0]);
        p.y = (f2bf(o[3]) << 16) | f2bf(o[2]);
        p.z = (f2bf(o[5]) << 16) | f2bf(o[4]);
        p.w = (f2bf(o[7]) << 16) | f2bf(o[6]);
        *(uintx4*)(out + (size_t)node * 64 + sl * 4) = p;
    }
}

// ---- fused CSR segsum + LN, D=64, fp32 out, no ReLU (final layer) ----------
// Same layout: g 0..3, sl 0..15, uintx2 = 8B/lane (2 sectors/edge), unroll-2.
__global__ __launch_bounds__(256) void agg_ln64(const unsigned int* __restrict__ xw,
                                                const int* __restrict__ ptr,
                                                const int* __restrict__ col,
                                                float* __restrict__ out, int N) {
    const int node = blockIdx.x * 4 + (threadIdx.x >> 6);
    if (node >= N) return;
    const int lane = threadIdx.x & 63;
    const int g  = lane >> 4;     // 0..3 edge group
    const int sl = lane & 15;     // 0..15 sublane (owns 4 features)
    const int s = ptr[node];
    const int e = ptr[node + 1];

    float accA[4] = {}, accB[4] = {};
    const unsigned int* base = xw + sl * 2;
    int i = s + g;
    for (; i + 4 < e; i += 8) {
        uintx2 v0 = *(const uintx2*)(base + (size_t)col[i] * 32);
        uintx2 v1 = *(const uintx2*)(base + (size_t)col[i + 4] * 32);
        accA[0] += bf_lo(v0.x); accA[1] += bf_hi(v0.x);
        accA[2] += bf_lo(v0.y); accA[3] += bf_hi(v0.y);
        accB[0] += bf_lo(v1.x); accB[1] += bf_hi(v1.x);
        accB[2] += bf_lo(v1.y); accB[3] += bf_hi(v1.y);
    }
    if (i < e) {
        uintx2 v0 = *(const uintx2*)(base + (size_t)col[i] * 32);
        accA[0] += bf_lo(v0.x); accA[1] += bf_hi(v0.x);
        accA[2] += bf_lo(v0.y); accA[3] += bf_hi(v0.y);
    }

    float acc[4];
    #pragma unroll
    for (int j = 0; j < 4; ++j) acc[j] = accA[j] + accB[j];

    #pragma unroll
    for (int j = 0; j < 4; ++j) {
        acc[j] += __shfl_xor(acc[j], 16, 64);
        acc[j] += __shfl_xor(acc[j], 32, 64);
    }
    float s1 = 0.f, s2 = 0.f;
    #pragma unroll
    for (int j = 0; j < 4; ++j) { s1 += acc[j]; s2 += acc[j] * acc[j]; }
    #pragma unroll
    for (int m = 8; m >= 1; m >>= 1) {
        s1 += __shfl_xor(s1, m, 64);
        s2 += __shfl_xor(s2, m, 64);
    }
    const float mean = s1 * (1.0f / 64.0f);
    const float var  = s2 * (1.0f / 64.0f) - mean * mean;
    const float inv  = rsqrtf(var + 1e-5f);

    if (g == 0) {
        float4 o;
        o.x = (acc[0] - mean) * inv;
        o.y = (acc[1] - mean) * inv;
        o.z = (acc[2] - mean) * inv;
        o.w = (acc[3] - mean) * inv;
        *(float4*)(out + (size_t)node * 64 + sl * 4) = o;
    }
}

extern "C" void kernel_launch(void* const* d_in, const int* in_sizes, int n_in,
                              void* d_out, int out_size, void* d_ws, size_t ws_size,
                              hipStream_t stream) {
    const float* feat = (const float*)d_in[0];   // [N,128]
    const float* W0   = (const float*)d_in[1];   // [128,128]
    const float* W1   = (const float*)d_in[2];   // [128,128]
    const float* W2   = (const float*)d_in[3];   // [128,64]
    const int*   ptr  = (const int*)d_in[4];     // [N+1]
    const int*   col  = (const int*)d_in[5];     // [E]
    // d_in[6] = edge_rows, unused (CSR ptr encodes the same segments)

    const int N = in_sizes[4] - 1;               // 50000

    unsigned int* xwp = (unsigned int*)d_ws;                 // [N,64] uint (bf16x2)
    unsigned int* hb  = xwp + (size_t)N * 64;                // [N,64] uint (bf16x2)
    unsigned int* fb  = hb + (size_t)N * 64;                 // [N,64] uint (bf16 feat)
    unsigned int* WtP = fb + (size_t)N * 64;                 // 3 x [128,64] uint
    float*        out = (float*)d_out;                       // [N,64]

    const int gemmBlocks = (N + 15) / 16;        // 3125 (1 wave each)
    const int nodeBlocks = (N + 3) / 4;          // 12500

    cvt_feat<<<(N * 16 + 255) / 256, 256, 0, stream>>>(feat, fb, N * 16);
    cvt_w<<<48, 256, 0, stream>>>(W0, W1, W2, WtP);

    // Layer 0
    gemm_mfma<128><<<gemmBlocks, 64, 0, stream>>>(fb, WtP, xwp, N);
    agg_ln128<<<nodeBlocks, 256, 0, stream>>>(xwp, ptr, col, hb, N);
    // Layer 1
    gemm_mfma<128><<<gemmBlocks, 64, 0, stream>>>(hb, WtP + 128 * 64, xwp, N);
    agg_ln128<<<nodeBlocks, 256, 0, stream>>>(xwp, ptr, col, hb, N);
    // Layer 2 (D_out=64, no ReLU, fp32 out)
    gemm_mfma<64><<<gemmBlocks, 64, 0, stream>>>(hb, WtP + 2 * 128 * 64, xwp, N);
    agg_ln64<<<nodeBlocks, 256, 0, stream>>>(xwp, ptr, col, out, N);
}